// Round 6
// baseline (165.492 us; speedup 1.0000x reference)
//
#include <hip/hip_runtime.h>
#include <math.h>

#define D_MODEL 300
#define LSEQ    512
#define NBATCH  300
#define SPLIT   8                   // gather l-chunks
#define LCH     (LSEQ / SPLIT)      // 64 l-values per gather block
#define PESPLIT 4                   // pe-term l-chunks
#define PLCH    (LSEQ / PESPLIT)    // 128 l-values per pe block
#define NG      4                   // parallel l-streams per gather block
#define NR      75                  // float4 lanes per row (75*4 = 300)
#define KCH     (D_MODEL / 4)       // 75, fc1 k-chunk
#define JPB     4                   // j-rows per fc1 block
#define SCALE   17.32050807568877f  // sqrt(300)

// pe[l, e]: e even -> sin(l * div[e/2]); e odd -> cos(l * div[e/2])
__global__ void pe_kernel(float* __restrict__ pe) {
    int idx = blockIdx.x * blockDim.x + threadIdx.x;
    if (idx >= LSEQ * D_MODEL) return;
    int l = idx / D_MODEL;
    int e = idx - l * D_MODEL;
    int k = e >> 1;
    float dv = expf((float)(2 * k) * (-9.210340371976184f / 300.0f));
    float arg = (float)l * dv;
    pe[idx] = (e & 1) ? cosf(arg) : sinf(arg);
}

// One dispatch, two block roles (overlapping L3-bound gather with L2-bound pe-term):
//  y <  SPLIT : Dm[i][e] += SCALE * sum_{l in 64-chunk} s[l] * emb1[x1[i,l]][e]
//  y >= SPLIT : Dm[i][e] += sum_{l in 128-chunk} s[l] * pe[l][e]
// where s[l] = emb2[x2[i,l], i]*SCALE + pe[l, i]
__global__ void diag_fused_kernel(const int* __restrict__ x1, const int* __restrict__ x2,
                                  const float* __restrict__ emb1, const float* __restrict__ emb2,
                                  const float* __restrict__ pe, float* __restrict__ Dm) {
    __shared__ int    x1ch[PLCH];
    __shared__ float  sch[PLCH];
    __shared__ float4 part[NG][NR];
    const int i   = blockIdx.x;   // batch index (== diagonal index)
    const int y   = blockIdx.y;
    const int tid = threadIdx.x;

    if (y < SPLIT) {
        // ---------------- gather role ----------------
        const int l0 = y * LCH;
        if (tid < LCH) {
            const int l = l0 + tid;
            x1ch[tid] = x1[i * LSEQ + l];
            int idx2  = x2[i * LSEQ + l];
            sch[tid]  = emb2[idx2 * D_MODEL + i] * SCALE + pe[l * D_MODEL + i];
        }
        __syncthreads();

        const int g = tid / NR;
        const int r = tid - g * NR;
        if (tid < NG * NR) {
            float ax = 0.f, ay = 0.f, az = 0.f, aw = 0.f;
            #pragma unroll 4
            for (int l = g; l < LCH; l += NG) {
                const float4 ev = ((const float4*)(emb1 + (size_t)x1ch[l] * D_MODEL))[r];
                const float  s  = sch[l];
                ax = fmaf(s, ev.x, ax);
                ay = fmaf(s, ev.y, ay);
                az = fmaf(s, ev.z, az);
                aw = fmaf(s, ev.w, aw);
            }
            part[g][r] = make_float4(ax, ay, az, aw);
        }
        __syncthreads();

        if (g == 0 && tid < NR) {
            float4 p0 = part[0][r], p1 = part[1][r], p2 = part[2][r], p3 = part[3][r];
            float* dst = Dm + i * D_MODEL + 4 * r;
            atomicAdd(dst + 0, SCALE * (p0.x + p1.x + p2.x + p3.x));
            atomicAdd(dst + 1, SCALE * (p0.y + p1.y + p2.y + p3.y));
            atomicAdd(dst + 2, SCALE * (p0.z + p1.z + p2.z + p3.z));
            atomicAdd(dst + 3, SCALE * (p0.w + p1.w + p2.w + p3.w));
        }
    } else {
        // ---------------- pe-term role ----------------
        const int l0 = (y - SPLIT) * PLCH;
        if (tid < PLCH) {
            const int l = l0 + tid;
            int idx2  = x2[i * LSEQ + l];
            sch[tid]  = emb2[idx2 * D_MODEL + i] * SCALE + pe[l * D_MODEL + i];
        }
        __syncthreads();

        if (tid < D_MODEL) {
            float acc = 0.0f;
            #pragma unroll 8
            for (int l = 0; l < PLCH; ++l)
                acc = fmaf(sch[l], pe[(l0 + l) * D_MODEL + tid], acc);
            atomicAdd(&Dm[i * D_MODEL + tid], acc);
        }
    }
}

// fc1 k-split partial, JPB j-rows per block for Dm reuse:
// Hpre[j][e] += sum_{k in chunk} w1[j,k] * Dm[k][e]
__global__ void fc1_kernel(const float* __restrict__ w1, const float* __restrict__ Dm,
                           float* __restrict__ Hpre) {
    const int j0  = blockIdx.x * JPB;
    const int sp  = blockIdx.y;
    const int tid = threadIdx.x;
    const int k0  = sp * KCH;
    if (tid >= D_MODEL) return;
    const float* w1r0 = w1 + (j0 + 0) * D_MODEL + k0;
    const float* w1r1 = w1 + (j0 + 1) * D_MODEL + k0;
    const float* w1r2 = w1 + (j0 + 2) * D_MODEL + k0;
    const float* w1r3 = w1 + (j0 + 3) * D_MODEL + k0;
    float acc0 = 0.0f, acc1 = 0.0f, acc2 = 0.0f, acc3 = 0.0f;
    #pragma unroll 5
    for (int k = 0; k < KCH; ++k) {
        float d = Dm[(k0 + k) * D_MODEL + tid];
        acc0 = fmaf(w1r0[k], d, acc0);
        acc1 = fmaf(w1r1[k], d, acc1);
        acc2 = fmaf(w1r2[k], d, acc2);
        acc3 = fmaf(w1r3[k], d, acc3);
    }
    atomicAdd(&Hpre[(j0 + 0) * D_MODEL + tid], acc0);
    atomicAdd(&Hpre[(j0 + 1) * D_MODEL + tid], acc1);
    atomicAdd(&Hpre[(j0 + 2) * D_MODEL + tid], acc2);
    atomicAdd(&Hpre[(j0 + 3) * D_MODEL + tid], acc3);
}

// Fused bias + relu + fc2 + softmax. Block = 256 thr = 64 e-lanes x 4 j-chunks.
__global__ void fc2_softmax_kernel(const float* __restrict__ Hpre, const float* __restrict__ b1,
                                   const float* __restrict__ w2, const float* __restrict__ b2,
                                   float* __restrict__ out) {
    __shared__ float sm[4][4][64];   // [jc][o][e_loc]
    const int tid   = threadIdx.x;
    const int e_loc = tid & 63;
    const int jc    = tid >> 6;
    const int e     = blockIdx.x * 64 + e_loc;

    float a0 = 0.f, a1 = 0.f, a2 = 0.f, a3 = 0.f;
    if (e < D_MODEL) {
        const int j0 = jc * 75;
        #pragma unroll 5
        for (int j = j0; j < j0 + 75; ++j) {
            float h = fmaxf(Hpre[j * D_MODEL + e] + b1[j], 0.0f);
            a0 = fmaf(h, w2[0 * D_MODEL + j], a0);
            a1 = fmaf(h, w2[1 * D_MODEL + j], a1);
            a2 = fmaf(h, w2[2 * D_MODEL + j], a2);
            a3 = fmaf(h, w2[3 * D_MODEL + j], a3);
        }
    }
    sm[jc][0][e_loc] = a0; sm[jc][1][e_loc] = a1;
    sm[jc][2][e_loc] = a2; sm[jc][3][e_loc] = a3;
    __syncthreads();

    if (jc == 0 && e < D_MODEL) {
        float l0 = b2[0] + sm[0][0][e_loc] + sm[1][0][e_loc] + sm[2][0][e_loc] + sm[3][0][e_loc];
        float l1 = b2[1] + sm[0][1][e_loc] + sm[1][1][e_loc] + sm[2][1][e_loc] + sm[3][1][e_loc];
        float l2 = b2[2] + sm[0][2][e_loc] + sm[1][2][e_loc] + sm[2][2][e_loc] + sm[3][2][e_loc];
        float l3 = b2[3] + sm[0][3][e_loc] + sm[1][3][e_loc] + sm[2][3][e_loc] + sm[3][3][e_loc];
        float m  = fmaxf(fmaxf(l0, l1), fmaxf(l2, l3));
        float x0 = expf(l0 - m), x1 = expf(l1 - m), x2 = expf(l2 - m), x3 = expf(l3 - m);
        float inv = 1.0f / (x0 + x1 + x2 + x3);
        out[e * 4 + 0] = x0 * inv;
        out[e * 4 + 1] = x1 * inv;
        out[e * 4 + 2] = x2 * inv;
        out[e * 4 + 3] = x3 * inv;
    }
}

extern "C" void kernel_launch(void* const* d_in, const int* in_sizes, int n_in,
                              void* d_out, int out_size, void* d_ws, size_t ws_size,
                              hipStream_t stream) {
    const int*   x1   = (const int*)d_in[0];
    const int*   x2   = (const int*)d_in[1];
    const float* emb1 = (const float*)d_in[2];
    const float* emb2 = (const float*)d_in[3];
    const float* w1   = (const float*)d_in[4];
    const float* b1   = (const float*)d_in[5];
    const float* w2   = (const float*)d_in[6];
    const float* b2   = (const float*)d_in[7];
    float* out = (float*)d_out;

    char* ws = (char*)d_ws;
    float* pe   = (float*)ws;                 // 512*300*4 = 614400 B
    float* Dm   = (float*)(ws + 614400);      // 300*300*4 = 360000 B
    float* Hpre = (float*)(ws + 974400);      // 300*300*4 = 360000 B

    // zero the two atomic-accumulated buffers (contiguous)
    (void)hipMemsetAsync(Dm, 0, 2 * 360000, stream);

    pe_kernel<<<(LSEQ * D_MODEL + 255) / 256, 256, 0, stream>>>(pe);
    diag_fused_kernel<<<dim3(NBATCH, SPLIT + PESPLIT), 320, 0, stream>>>(x1, x2, emb1, emb2, pe, Dm);
    fc1_kernel<<<dim3(D_MODEL / JPB, 4), 320, 0, stream>>>(w1, Dm, Hpre);
    fc2_softmax_kernel<<<(D_MODEL + 63) / 64, 256, 0, stream>>>(Hpre, b1, w2, b2, out);
}

// Round 7
// 159.638 us; speedup vs baseline: 1.0367x; 1.0367x over previous
//
#include <hip/hip_runtime.h>
#include <math.h>

#define D_MODEL 300
#define LSEQ    512
#define NBATCH  300
#define VOCAB   32000
#define SPLIT   8                   // l-chunks for diag
#define LCH     (LSEQ / SPLIT)      // 64 l-values per block
#define NG      4                   // parallel l-streams per block
#define NR      75                  // 8B-vec lanes per row (75*4 = 300 elems)
#define KCH     (D_MODEL / 4)       // 75, fc1 k-chunk
#define JPB     4                   // j-rows per fc1 block
#define SCALE   17.32050807568877f  // sqrt(300)

__device__ __forceinline__ unsigned short f2bf(float f) {
    unsigned u = __float_as_uint(f);
    unsigned r = (u + 0x7FFFu + ((u >> 16) & 1u)) >> 16;   // round-nearest-even
    return (unsigned short)r;
}
__device__ __forceinline__ float bf2f(unsigned short v) {
    return __uint_as_float(((unsigned)v) << 16);
}

// emb1 (f32, 9.6M elems) -> bf16 slab. 4 elems per thread.
__global__ void conv_kernel(const float* __restrict__ emb1, unsigned short* __restrict__ e1b) {
    int t = blockIdx.x * blockDim.x + threadIdx.x;
    int base = t * 4;
    if (base >= VOCAB * D_MODEL) return;
    float4 v = ((const float4*)emb1)[t];
    ushort4 o;
    o.x = f2bf(v.x); o.y = f2bf(v.y); o.z = f2bf(v.z); o.w = f2bf(v.w);
    ((ushort4*)e1b)[t] = o;
}

// pe[l, e]: e even -> sin(l * div[e/2]); e odd -> cos(l * div[e/2])
__global__ void pe_kernel(float* __restrict__ pe) {
    int idx = blockIdx.x * blockDim.x + threadIdx.x;
    if (idx >= LSEQ * D_MODEL) return;
    int l = idx / D_MODEL;
    int e = idx - l * D_MODEL;
    int k = e >> 1;
    float dv = expf((float)(2 * k) * (-9.210340371976184f / 300.0f));
    float arg = (float)l * dv;
    pe[idx] = (e & 1) ? cosf(arg) : sinf(arg);
}

// Dm[i][e] += sum_{l in chunk} s[l] * (SCALE*emb1[x1[i,l]][e] + pe[l][e])
// bf16 ushort4 gather (8B) + f32 pe (L2-resident); 4 l-streams; LDS reduce.
__global__ void diag_fused_kernel(const int* __restrict__ x1, const int* __restrict__ x2,
                                  const unsigned short* __restrict__ e1b,
                                  const float* __restrict__ emb2,
                                  const float* __restrict__ pe, float* __restrict__ Dm) {
    __shared__ int    x1ch[LCH];
    __shared__ float  sch[LCH];
    __shared__ float4 part[NG][NR];
    const int i   = blockIdx.x;   // batch index (== diagonal index)
    const int sp  = blockIdx.y;   // l-chunk
    const int tid = threadIdx.x;
    const int l0  = sp * LCH;

    if (tid < LCH) {
        const int l = l0 + tid;
        x1ch[tid] = x1[i * LSEQ + l];
        int idx2  = x2[i * LSEQ + l];
        sch[tid]  = emb2[idx2 * D_MODEL + i] * SCALE + pe[l * D_MODEL + i];
    }
    __syncthreads();

    const int g = tid / NR;       // l-stream
    const int r = tid - g * NR;   // 4-elem vec index within row

    if (tid < NG * NR) {
        float ax = 0.f, ay = 0.f, az = 0.f, aw = 0.f;
        #pragma unroll 4
        for (int l = g; l < LCH; l += NG) {
            const ushort4 ev = ((const ushort4*)(e1b + (size_t)x1ch[l] * D_MODEL))[r];
            const float4  pv = ((const float4*)(pe + (size_t)(l0 + l) * D_MODEL))[r];
            const float   s  = sch[l];
            ax = fmaf(s, fmaf(bf2f(ev.x), SCALE, pv.x), ax);
            ay = fmaf(s, fmaf(bf2f(ev.y), SCALE, pv.y), ay);
            az = fmaf(s, fmaf(bf2f(ev.z), SCALE, pv.z), az);
            aw = fmaf(s, fmaf(bf2f(ev.w), SCALE, pv.w), aw);
        }
        part[g][r] = make_float4(ax, ay, az, aw);
    }
    __syncthreads();

    if (g == 0 && tid < NR) {
        float4 p0 = part[0][r], p1 = part[1][r], p2 = part[2][r], p3 = part[3][r];
        float* dst = Dm + i * D_MODEL + 4 * r;
        atomicAdd(dst + 0, p0.x + p1.x + p2.x + p3.x);
        atomicAdd(dst + 1, p0.y + p1.y + p2.y + p3.y);
        atomicAdd(dst + 2, p0.z + p1.z + p2.z + p3.z);
        atomicAdd(dst + 3, p0.w + p1.w + p2.w + p3.w);
    }
}

// fc1 k-split partial, JPB j-rows per block for Dm reuse:
// Hpre[j][e] += sum_{k in chunk} w1[j,k] * Dm[k][e]
__global__ void fc1_kernel(const float* __restrict__ w1, const float* __restrict__ Dm,
                           float* __restrict__ Hpre) {
    const int j0  = blockIdx.x * JPB;
    const int sp  = blockIdx.y;
    const int tid = threadIdx.x;
    const int k0  = sp * KCH;
    if (tid >= D_MODEL) return;
    const float* w1r0 = w1 + (j0 + 0) * D_MODEL + k0;
    const float* w1r1 = w1 + (j0 + 1) * D_MODEL + k0;
    const float* w1r2 = w1 + (j0 + 2) * D_MODEL + k0;
    const float* w1r3 = w1 + (j0 + 3) * D_MODEL + k0;
    float acc0 = 0.0f, acc1 = 0.0f, acc2 = 0.0f, acc3 = 0.0f;
    #pragma unroll 5
    for (int k = 0; k < KCH; ++k) {
        float d = Dm[(k0 + k) * D_MODEL + tid];
        acc0 = fmaf(w1r0[k], d, acc0);
        acc1 = fmaf(w1r1[k], d, acc1);
        acc2 = fmaf(w1r2[k], d, acc2);
        acc3 = fmaf(w1r3[k], d, acc3);
    }
    atomicAdd(&Hpre[(j0 + 0) * D_MODEL + tid], acc0);
    atomicAdd(&Hpre[(j0 + 1) * D_MODEL + tid], acc1);
    atomicAdd(&Hpre[(j0 + 2) * D_MODEL + tid], acc2);
    atomicAdd(&Hpre[(j0 + 3) * D_MODEL + tid], acc3);
}

// Fused bias + relu + fc2 + softmax. Block = 256 thr = 64 e-lanes x 4 j-chunks.
__global__ void fc2_softmax_kernel(const float* __restrict__ Hpre, const float* __restrict__ b1,
                                   const float* __restrict__ w2, const float* __restrict__ b2,
                                   float* __restrict__ out) {
    __shared__ float sm[4][4][64];   // [jc][o][e_loc]
    const int tid   = threadIdx.x;
    const int e_loc = tid & 63;
    const int jc    = tid >> 6;
    const int e     = blockIdx.x * 64 + e_loc;

    float a0 = 0.f, a1 = 0.f, a2 = 0.f, a3 = 0.f;
    if (e < D_MODEL) {
        const int j0 = jc * 75;
        #pragma unroll 5
        for (int j = j0; j < j0 + 75; ++j) {
            float h = fmaxf(Hpre[j * D_MODEL + e] + b1[j], 0.0f);
            a0 = fmaf(h, w2[0 * D_MODEL + j], a0);
            a1 = fmaf(h, w2[1 * D_MODEL + j], a1);
            a2 = fmaf(h, w2[2 * D_MODEL + j], a2);
            a3 = fmaf(h, w2[3 * D_MODEL + j], a3);
        }
    }
    sm[jc][0][e_loc] = a0; sm[jc][1][e_loc] = a1;
    sm[jc][2][e_loc] = a2; sm[jc][3][e_loc] = a3;
    __syncthreads();

    if (jc == 0 && e < D_MODEL) {
        float l0 = b2[0] + sm[0][0][e_loc] + sm[1][0][e_loc] + sm[2][0][e_loc] + sm[3][0][e_loc];
        float l1 = b2[1] + sm[0][1][e_loc] + sm[1][1][e_loc] + sm[2][1][e_loc] + sm[3][1][e_loc];
        float l2 = b2[2] + sm[0][2][e_loc] + sm[1][2][e_loc] + sm[2][2][e_loc] + sm[3][2][e_loc];
        float l3 = b2[3] + sm[0][3][e_loc] + sm[1][3][e_loc] + sm[2][3][e_loc] + sm[3][3][e_loc];
        float m  = fmaxf(fmaxf(l0, l1), fmaxf(l2, l3));
        float x0 = expf(l0 - m), x1 = expf(l1 - m), x2 = expf(l2 - m), x3 = expf(l3 - m);
        float inv = 1.0f / (x0 + x1 + x2 + x3);
        out[e * 4 + 0] = x0 * inv;
        out[e * 4 + 1] = x1 * inv;
        out[e * 4 + 2] = x2 * inv;
        out[e * 4 + 3] = x3 * inv;
    }
}

extern "C" void kernel_launch(void* const* d_in, const int* in_sizes, int n_in,
                              void* d_out, int out_size, void* d_ws, size_t ws_size,
                              hipStream_t stream) {
    const int*   x1   = (const int*)d_in[0];
    const int*   x2   = (const int*)d_in[1];
    const float* emb1 = (const float*)d_in[2];
    const float* emb2 = (const float*)d_in[3];
    const float* w1   = (const float*)d_in[4];
    const float* b1   = (const float*)d_in[5];
    const float* w2   = (const float*)d_in[6];
    const float* b2   = (const float*)d_in[7];
    float* out = (float*)d_out;

    char* ws = (char*)d_ws;
    float*          pe   = (float*)ws;                  // 512*300*4 = 614400 B
    float*          Dm   = (float*)(ws + 614400);       // 300*300*4 = 360000 B
    float*          Hpre = (float*)(ws + 974400);       // 300*300*4 = 360000 B
    unsigned short* e1b  = (unsigned short*)(ws + 1334400);  // 32000*300*2 = 19.2 MB

    // zero the two atomic-accumulated buffers (contiguous)
    (void)hipMemsetAsync(Dm, 0, 2 * 360000, stream);

    conv_kernel<<<(VOCAB * D_MODEL / 4 + 255) / 256, 256, 0, stream>>>(emb1, e1b);
    pe_kernel<<<(LSEQ * D_MODEL + 255) / 256, 256, 0, stream>>>(pe);
    diag_fused_kernel<<<dim3(NBATCH, SPLIT), 320, 0, stream>>>(x1, x2, e1b, emb2, pe, Dm);
    fc1_kernel<<<dim3(D_MODEL / JPB, 4), 320, 0, stream>>>(w1, Dm, Hpre);
    fc2_softmax_kernel<<<(D_MODEL + 63) / 64, 256, 0, stream>>>(Hpre, b1, w2, b2, out);
}